// Round 4
// baseline (1714.571 us; speedup 1.0000x reference)
//
#include <hip/hip_runtime.h>
#include <math.h>

#define TPB 256

// ---- flat LDS layout (floats). total 13152 floats = 52608 B -> 3 blocks/CU
constexpr int O_X   = 0;            // x[48][18]                       (864)
constexpr int O_XM  = 864;          // mLSTM xm[48][36]                (1728)
constexpr int O_H   = 864 + 1728;   // h[48][18]                       (864)
constexpr int O_CM  = 864;          // attention C[48][49] overlays XM+H (2352<=2592)
constexpr int O_Z   = 3456;         // z[48][36]                       (1728)
constexpr int O_XC  = 3456 + 1728;  // xc[48][36]                      (1728)
constexpr int O_WX  = 3456;         // sLSTM wx[2][48][36] overlays Z+XC (3456)
constexpr int O_FFN = 3456;         // FFN act[48][64] overlays Z+XC   (3072)
constexpr int O_Q   = 6912;         // q[48][38] (stride 38: float2-aligned)
constexpr int O_K   = 6912 + 1824;  // k[48][38]
constexpr int O_V   = 6912 + 3648;  // v[48][38]
constexpr int O_HC  = O_V;          // sLSTM hc[48][18] overlays V     (864)
constexpr int O_YS  = O_V + 864;    // sLSTM ys[48][18]                (864)
constexpr int O_WSTG= O_Q;          // weight staging overlay (dead-Q phases only)
constexpr int O_IPRE= 12384;        // [2][48]
constexpr int O_FPRE= 12480;
constexpr int O_LFC = 12576;
constexpr int O_MR  = 12672;
constexpr int O_ROW = 12768;        // rowsum [2][48]
constexpr int O_AB  = 12864;        // gate fold weights [2g][2h][2w][36] (288)
constexpr int LDS_FLOATS = 13152;

__device__ __forceinline__ float fast_sigmoid(float x){ return 1.f/(1.f+__expf(-x)); }
__device__ __forceinline__ float fast_silu(float x){ return x/(1.f+__expf(-x)); }
__device__ __forceinline__ float log_sigmoid(float x){ return fminf(x,0.f) - log1pf(__expf(-fabsf(x))); }

// LN(x)*w -> h  (48 rows, threads 0..47)
__device__ __forceinline__ void ln_rows(float* L, int tid, const float* __restrict__ w){
  if (tid < 48){
    const int s = tid;
    float mu = 0.f;
    #pragma unroll
    for (int d=0; d<18; ++d) mu += L[O_X+s*18+d];
    mu *= (1.f/18.f);
    float var = 0.f;
    #pragma unroll
    for (int d=0; d<18; ++d){ float t = L[O_X+s*18+d]-mu; var += t*t; }
    var *= (1.f/18.f);
    const float r = rsqrtf(var + 1e-5f);
    #pragma unroll
    for (int d=0; d<18; ++d) L[O_H+s*18+d] = (L[O_X+s*18+d]-mu)*r*w[d];
  }
}

__device__ void mlstm_block(float* L, int tid,
    const float* __restrict__ lnw, const float* __restrict__ upw,
    const float* __restrict__ cw,  const float* __restrict__ cb,
    const float* __restrict__ qw,  const float* __restrict__ kw,
    const float* __restrict__ vw,  const float* __restrict__ igw,
    const float* __restrict__ igb, const float* __restrict__ fgw,
    const float* __restrict__ fgb, const float* __restrict__ skp,
    const float* __restrict__ onw, const float* __restrict__ dwn)
{
  // P1: LN (threads<48) + AB gate-fold precompute + upw staging (threads>=48)
  ln_rows(L, tid, lnw);
  if (tid >= 48){
    for (int i = tid-48; i < 288; i += 208){
      const int g = i/144, rem = i%144, h = rem/72, w2 = (rem%72)/36, c = rem%36;
      const int n = c>>2, d = c&3;
      const float* gatew = (g ? fgw : igw) + h*108;
      float val = 0.f;
      if (w2 == 0){
        #pragma unroll
        for (int o=0;o<4;++o) val += qw[n*16+o*4+d]*gatew[n*4+o] + kw[n*16+o*4+d]*gatew[36+n*4+o];
      } else {
        #pragma unroll
        for (int o=0;o<4;++o) val += vw[n*16+o*4+d]*gatew[72+n*4+o];
      }
      L[O_AB + ((g*2+h)*2+w2)*36 + c] = val;
    }
    for (int i = tid-48; i < 1296; i += 208) L[O_WSTG+i] = upw[i];  // stage (18x72)
  }
  __syncthreads();

  // P2: up-projection (48x18)@(18x72) -> xm | z.  thread = (o, 16-row chunk)
  // weights read from LDS stage (broadcast across sg groups, <=2-way banks)
  if (tid < 216){
    const int o = tid%72, sg = tid/72;
    for (int s=sg*16; s<sg*16+16; ++s){
      const float2* hp = reinterpret_cast<const float2*>(&L[O_H + s*18]);
      float acc = 0.f;
      #pragma unroll
      for (int d2=0; d2<9; ++d2){
        float2 hv = hp[d2];
        acc += hv.x*L[O_WSTG+(2*d2)*72+o] + hv.y*L[O_WSTG+(2*d2+1)*72+o];
      }
      if (o < 36) L[O_XM + s*36 + o] = acc; else L[O_Z + s*36 + (o-36)] = acc;
    }
  }
  __syncthreads();

  // P3: causal depthwise conv(k=4)+bias+silu on xm -> xc
  for (int i=tid; i<48*36; i+=TPB){
    const int s=i/36, c=i%36;
    float acc = cb[c];
    #pragma unroll
    for (int j=0; j<4; ++j){ const int sp=s-3+j; if (sp>=0) acc += L[O_XM+sp*36+c]*cw[c*4+j]; }
    L[O_XC+s*36+c] = fast_silu(acc);
  }
  __syncthreads();

  // P4: qkv (all threads) + gates via AB fold (threads<192)
  for (int i=tid; i<48*36; i+=TPB){
    const int s=i/36, c=i%36, n=c>>2, o=c&3;
    const float4 xcv = *reinterpret_cast<const float4*>(&L[O_XC+s*36+n*4]);
    const float4 xmv = *reinterpret_cast<const float4*>(&L[O_XM+s*36+n*4]);
    float aq = xcv.x*qw[n*16+o*4+0] + xcv.y*qw[n*16+o*4+1] + xcv.z*qw[n*16+o*4+2] + xcv.w*qw[n*16+o*4+3];
    float ak = xcv.x*kw[n*16+o*4+0] + xcv.y*kw[n*16+o*4+1] + xcv.z*kw[n*16+o*4+2] + xcv.w*kw[n*16+o*4+3];
    float av = xmv.x*vw[n*16+o*4+0] + xmv.y*vw[n*16+o*4+1] + xmv.z*vw[n*16+o*4+2] + xmv.w*vw[n*16+o*4+3];
    L[O_Q+s*38+c]=aq; L[O_K+s*38+c]=ak; L[O_V+s*38+c]=av;
  }
  if (tid < 192){
    const int g = tid/96, h = (tid/48)&1, s = tid%48;
    const float4* xcr = reinterpret_cast<const float4*>(&L[O_XC+s*36]);
    const float4* xmr = reinterpret_cast<const float4*>(&L[O_XM+s*36]);
    const float4* Ar  = reinterpret_cast<const float4*>(&L[O_AB + ((g*2+h)*2+0)*36]);
    const float4* Br  = reinterpret_cast<const float4*>(&L[O_AB + ((g*2+h)*2+1)*36]);
    float acc = g ? fgb[h] : igb[h];
    #pragma unroll
    for (int c4=0;c4<9;++c4){
      float4 a = xcr[c4], wa = Ar[c4];
      acc += a.x*wa.x + a.y*wa.y + a.z*wa.z + a.w*wa.w;
      float4 b = xmr[c4], wb = Br[c4];
      acc += b.x*wb.x + b.y*wb.y + b.z*wb.z + b.w*wb.w;
    }
    if (g) L[O_FPRE+h*48+s]=acc; else L[O_IPRE+h*48+s]=acc;
  }
  __syncthreads();

  // P5: per-head wave prefix scans: lfc = cumsum(logsig(fpre)); mr = lfc + cummax(ipre-lfc)
  if (tid < 128){
    const int h = tid>>6, lane = tid&63;
    float ls = (lane<48) ? log_sigmoid(L[O_FPRE+h*48+lane]) : 0.f;
    #pragma unroll
    for (int off=1; off<64; off<<=1){ float t = __shfl_up(ls, off); if (lane>=off) ls += t; }
    if (lane<48) L[O_LFC+h*48+lane] = ls;
    float u = (lane<48) ? (L[O_IPRE+h*48+lane] - ls) : -1e30f;
    #pragma unroll
    for (int off=1; off<64; off<<=1){ float t = __shfl_up(u, off); if (lane>=off) u = fmaxf(u,t); }
    if (lane<48) L[O_MR+h*48+lane] = ls + u;
  }
  __syncthreads();

  // P6: attention per head: stage A (balanced C cells, float2 qk), stage B (PV d-pairs)
  for (int h=0; h<2; ++h){
    for (int i=tid; i<1176; i+=TPB){
      const int r=i/49, j=i%49;
      const int s = (j<=r) ? r : 47-r;
      const int t = (j<=r) ? j : j-r-1;
      const float l = L[O_LFC+h*48+s] - L[O_LFC+h*48+t] + L[O_IPRE+h*48+t];
      const float2* q2 = reinterpret_cast<const float2*>(&L[O_Q+s*38+h*18]);
      const float2* k2 = reinterpret_cast<const float2*>(&L[O_K+t*38+h*18]);
      float qk = 0.f;
      #pragma unroll
      for (int d=0; d<9; ++d){ float2 a=q2[d], b=k2[d]; qk += a.x*b.x + a.y*b.y; }
      L[O_CM + s*49 + t] = qk * 0.23570226039551584f * __expf(l - L[O_MR+h*48+s]);
    }
    __syncthreads();
    // PV + rowsum: task = (row, slot); slot<9 -> d-pair 2*slot, slot==9 -> rowsum
    for (int i=tid; i<480; i+=TPB){
      const int srow=i/10, slot=i%10;
      const int cb = O_CM+srow*49;
      if (slot < 9){
        const float2* v2 = reinterpret_cast<const float2*>(&L[O_V+h*18+2*slot]);
        float ax=0.f, ay=0.f;
        for (int t=0; t<=srow; ++t){
          const float cc = L[cb+t];
          const float2 v = v2[t*19];           // stride 38 floats = 19 float2
          ax += cc*v.x; ay += cc*v.y;
        }
        L[O_Q+srow*38+h*18+2*slot]   = ax;     // own-head q dead after stage A
        L[O_Q+srow*38+h*18+2*slot+1] = ay;
      } else {
        float acc = 0.f;
        for (int t=0; t<=srow; ++t) acc += L[cb+t];
        L[O_ROW+h*48+srow] = acc;
      }
    }
    __syncthreads();
  }

  // P7: normalize + per-(head,row) LN * onw, in place on q
  if (tid < 96){
    const int h = tid&1, s = tid>>1;
    const float nrm = fmaxf(fabsf(L[O_ROW+h*48+s]), __expf(-L[O_MR+h*48+s]));
    const float ninv = 1.f/(nrm + 1e-6f);
    float a[18]; float mu=0.f;
    #pragma unroll
    for (int d=0; d<18; ++d){ a[d] = L[O_Q+s*38+h*18+d]*ninv; mu += a[d]; }
    mu *= (1.f/18.f);
    float var=0.f;
    #pragma unroll
    for (int d=0; d<18; ++d){ float t=a[d]-mu; var += t*t; }
    var *= (1.f/18.f);
    const float r = rsqrtf(var + 1e-5f);
    #pragma unroll
    for (int d=0; d<18; ++d) L[O_Q+s*38+h*18+d] = (a[d]-mu)*r*onw[h*18+d];
  }
  __syncthreads();

  // P8: hst = (hn + skip*xc) * silu(z) -> xc (in place)
  for (int i=tid; i<48*36; i+=TPB){
    const int s=i/36, c=i%36;
    L[O_XC+s*36+c] = (L[O_Q+s*38+c] + skp[c]*L[O_XC+s*36+c]) * fast_silu(L[O_Z+s*36+c]);
  }
  __syncthreads();

  // P9: stage dwn (36x18) into dead-Q, then down-projection + residual
  for (int i=tid; i<648; i+=TPB) L[O_WSTG+i] = dwn[i];
  __syncthreads();
  if (tid < 216){
    const int e = tid%18, sg = tid/18;
    for (int s=sg*4; s<sg*4+4; ++s){
      const float4* xr = reinterpret_cast<const float4*>(&L[O_XC+s*36]);
      float acc = 0.f;
      #pragma unroll
      for (int c4=0; c4<9; ++c4){
        float4 v = xr[c4];
        acc += v.x*L[O_WSTG+(4*c4+0)*18+e] + v.y*L[O_WSTG+(4*c4+1)*18+e]
             + v.z*L[O_WSTG+(4*c4+2)*18+e] + v.w*L[O_WSTG+(4*c4+3)*18+e];
      }
      L[O_X+s*18+e] += acc;
    }
  }
  __syncthreads();
}

__device__ void slstm_block(float* L, int tid,
    const float* __restrict__ lnw, const float* __restrict__ cw, const float* __restrict__ cb,
    const float* __restrict__ gw,  const float* __restrict__ rw, const float* __restrict__ gb,
    const float* __restrict__ gnw, const float* __restrict__ flnw,
    const float* __restrict__ fup, const float* __restrict__ fdw)
{
  // S1: LN
  ln_rows(L, tid, lnw);
  __syncthreads();

  // S2: causal conv(E=18)+silu on h -> hc
  for (int i=tid; i<48*18; i+=TPB){
    const int s=i/18, c=i%18;
    float acc = cb[c];
    #pragma unroll
    for (int j=0; j<4; ++j){ const int sp=s-3+j; if (sp>=0) acc += L[O_H+sp*18+c]*cw[c*4+j]; }
    L[O_HC+s*18+c] = fast_silu(acc);
  }
  __syncthreads();

  // S3: wx (+bias): wx[h][s][g*9+e]; gates 0,1 from hc; 2,3 from h
  for (int i=tid; i<2*48*36; i+=TPB){
    const int h = i/1728, rem = i%1728, s = rem/36, ge = rem%36, g = ge/9, e = ge%9;
    const int base = (g<2) ? O_HC : O_H;
    const float* wv = gw + ((g*2+h)*9+e)*9;
    float acc = gb[(g*2+h)*9+e];
    #pragma unroll
    for (int d=0; d<9; ++d) acc += L[base + s*18 + h*9 + d]*wv[d];
    L[O_WX + (h*48+s)*36 + ge] = acc;
  }
  __syncthreads();

  // S4: recurrent scan — one wave per head, pure shuffles, no barriers inside
  if (tid < 128){
    const int h = tid>>6, lane = tid&63;
    const int g = lane/9, e = lane%9;   // valid for lane<36
    float rwreg[9];
    if (lane < 36){
      #pragma unroll
      for (int d=0; d<9; ++d) rwreg[d] = rw[((h*9+d)*4+g)*9+e];
    } else {
      #pragma unroll
      for (int d=0; d<9; ++d) rwreg[d] = 0.f;
    }
    float yS=0.f, cS=0.f, nS=0.f, mS=0.f;
    for (int s=0; s<48; ++s){
      float raw = (lane<36) ? L[O_WX + (h*48+s)*36 + lane] : 0.f;
      #pragma unroll
      for (int d=0; d<9; ++d){ float yd = __shfl(yS, d); raw += yd*rwreg[d]; }
      const float i_ = __shfl(raw, e);
      const float f_ = __shfl(raw, 9+e);
      const float z_ = __shfl(raw, 18+e);
      const float o_ = __shfl(raw, 27+e);
      const float lfm = mS + log_sigmoid(f_);
      const float mn  = fmaxf(i_, lfm);
      const float ig  = __expf(i_-mn), fg = __expf(lfm-mn);
      const float th  = 1.f - 2.f/(__expf(2.f*z_)+1.f);
      cS = fg*cS + ig*th;
      nS = fg*nS + ig;
      mS = mn;
      yS = fast_sigmoid(o_)*cS/nS;
      if (lane < 9) L[O_YS + s*18 + h*9 + lane] = yS;
    }
  }
  __syncthreads();

  // S5: group norm over 9 per (s,h) * gnw, residual into x
  if (tid < 96){
    const int s=tid>>1, h=tid&1;
    float mu=0.f;
    #pragma unroll
    for (int e=0; e<9; ++e) mu += L[O_YS+s*18+h*9+e];
    mu *= (1.f/9.f);
    float var=0.f;
    #pragma unroll
    for (int e=0; e<9; ++e){ float t=L[O_YS+s*18+h*9+e]-mu; var += t*t; }
    var *= (1.f/9.f);
    const float r = rsqrtf(var + 1e-5f);
    #pragma unroll
    for (int e=0; e<9; ++e) L[O_X+s*18+h*9+e] += (L[O_YS+s*18+h*9+e]-mu)*r*gnw[h*9+e];
  }
  __syncthreads();

  // S6: FFN LN (threads<48) + stage fup (18x128 = 2304 floats, threads>=48)
  ln_rows(L, tid, flnw);
  if (tid >= 48){
    for (int i=tid-48; i<2304; i+=208) L[O_WSTG+i] = fup[i];
  }
  __syncthreads();

  // S7: FFN up: act = gelu(h@Wg) * (h@Wu).  thread = (f, 12-row chunk); W from LDS
  {
    const int f = tid&63, sg = tid>>6;
    for (int s=sg*12; s<sg*12+12; ++s){
      const float2* hp = reinterpret_cast<const float2*>(&L[O_H + s*18]);
      float ug=0.f, uu=0.f;
      #pragma unroll
      for (int d2=0; d2<9; ++d2){
        float2 hv = hp[d2];
        ug += hv.x*L[O_WSTG+(2*d2)*128+f]    + hv.y*L[O_WSTG+(2*d2+1)*128+f];
        uu += hv.x*L[O_WSTG+(2*d2)*128+64+f] + hv.y*L[O_WSTG+(2*d2+1)*128+64+f];
      }
      const float ge = 0.5f*ug*(1.f + erff(ug*0.70710678118654752f));
      L[O_FFN + s*64 + f] = ge*uu;
    }
  }
  __syncthreads();

  // S8: stage fdw (64x18 = 1152), then FFN down + residual. thread = (e, 4-row chunk)
  for (int i=tid; i<1152; i+=TPB) L[O_WSTG+i] = fdw[i];
  __syncthreads();
  if (tid < 216){
    const int e = tid%18, sg = tid/18;
    for (int s=sg*4; s<sg*4+4; ++s){
      const float4* fr = reinterpret_cast<const float4*>(&L[O_FFN+s*64]);
      float acc = 0.f;
      #pragma unroll
      for (int c4=0; c4<16; ++c4){
        float4 v = fr[c4];
        acc += v.x*L[O_WSTG+(4*c4+0)*18+e] + v.y*L[O_WSTG+(4*c4+1)*18+e]
             + v.z*L[O_WSTG+(4*c4+2)*18+e] + v.w*L[O_WSTG+(4*c4+3)*18+e];
      }
      L[O_X+s*18+e] += acc;
    }
  }
  __syncthreads();
}

extern "C" __global__ void __launch_bounds__(TPB)
xlstm_kernel(const float* __restrict__ gx,
             const float* __restrict__ m_ln_w,  const float* __restrict__ m_up_w,
             const float* __restrict__ m_conv_w,const float* __restrict__ m_conv_b,
             const float* __restrict__ m_q_w,   const float* __restrict__ m_k_w,
             const float* __restrict__ m_v_w,   const float* __restrict__ m_ig_w,
             const float* __restrict__ m_ig_b,  const float* __restrict__ m_fg_w,
             const float* __restrict__ m_fg_b,  const float* __restrict__ m_skip,
             const float* __restrict__ m_on_w,  const float* __restrict__ m_down_w,
             const float* __restrict__ s_ln_w,  const float* __restrict__ s_conv_w,
             const float* __restrict__ s_conv_b,const float* __restrict__ s_gate_w,
             const float* __restrict__ s_rec_w, const float* __restrict__ s_bias,
             const float* __restrict__ s_gn_w,  const float* __restrict__ f_ln_w,
             const float* __restrict__ f_up_w,  const float* __restrict__ f_down_w,
             const float* __restrict__ post_ln_w, const float* __restrict__ dense_w,
             const float* __restrict__ dense_b, float* __restrict__ gout)
{
  __shared__ float L[LDS_FLOATS];
  const int tid = threadIdx.x;
  const int b = blockIdx.x;

  for (int i=tid; i<48*18; i+=TPB) L[O_X+i] = gx[b*864 + i];
  __syncthreads();

  int mj = 0;
  for (int blk=0; blk<7; ++blk){
    if (blk == 1){
      slstm_block(L, tid, s_ln_w, s_conv_w, s_conv_b, s_gate_w, s_rec_w, s_bias,
                  s_gn_w, f_ln_w, f_up_w, f_down_w);
    } else {
      mlstm_block(L, tid,
        m_ln_w + mj*18,       m_up_w + mj*(18*72),
        m_conv_w + mj*(36*4), m_conv_b + mj*36,
        m_q_w + mj*144,       m_k_w + mj*144,   m_v_w + mj*144,
        m_ig_w + mj*216,      m_ig_b + mj*2,
        m_fg_w + mj*216,      m_fg_b + mj*2,
        m_skip + mj*36,       m_on_w + mj*36,   m_down_w + mj*(36*18));
      ++mj;
    }
  }

  // final: post-LN, dense (18->1), zero s<24
  if (tid < 48){
    const int s = tid;
    float mu=0.f;
    #pragma unroll
    for (int d=0; d<18; ++d) mu += L[O_X+s*18+d];
    mu *= (1.f/18.f);
    float var=0.f;
    #pragma unroll
    for (int d=0; d<18; ++d){ float t=L[O_X+s*18+d]-mu; var += t*t; }
    var *= (1.f/18.f);
    const float r = rsqrtf(var + 1e-5f);
    float acc = dense_b[0];
    #pragma unroll
    for (int d=0; d<18; ++d) acc += (L[O_X+s*18+d]-mu)*r*post_ln_w[d]*dense_w[d];
    gout[b*48 + s] = (s < 24) ? 0.f : acc;
  }
}

extern "C" void kernel_launch(void* const* d_in, const int* in_sizes, int n_in,
                              void* d_out, int out_size, void* d_ws, size_t ws_size,
                              hipStream_t stream)
{
  const float* gx        = (const float*)d_in[0];
  const float* m_ln_w    = (const float*)d_in[1];
  const float* m_up_w    = (const float*)d_in[2];
  const float* m_conv_w  = (const float*)d_in[3];
  const float* m_conv_b  = (const float*)d_in[4];
  const float* m_q_w     = (const float*)d_in[5];
  const float* m_k_w     = (const float*)d_in[6];
  const float* m_v_w     = (const float*)d_in[7];
  const float* m_ig_w    = (const float*)d_in[8];
  const float* m_ig_b    = (const float*)d_in[9];
  const float* m_fg_w    = (const float*)d_in[10];
  const float* m_fg_b    = (const float*)d_in[11];
  const float* m_skip    = (const float*)d_in[12];
  const float* m_on_w    = (const float*)d_in[13];
  const float* m_down_w  = (const float*)d_in[14];
  const float* s_ln_w    = (const float*)d_in[15];
  const float* s_conv_w  = (const float*)d_in[16];
  const float* s_conv_b  = (const float*)d_in[17];
  const float* s_gate_w  = (const float*)d_in[18];
  const float* s_rec_w   = (const float*)d_in[19];
  const float* s_bias    = (const float*)d_in[20];
  const float* s_gn_w    = (const float*)d_in[21];
  const float* f_ln_w    = (const float*)d_in[22];
  const float* f_up_w    = (const float*)d_in[23];
  const float* f_down_w  = (const float*)d_in[24];
  const float* post_ln_w = (const float*)d_in[25];
  const float* dense_w   = (const float*)d_in[26];
  const float* dense_b   = (const float*)d_in[27];

  const int B = in_sizes[0] / (48*18);
  xlstm_kernel<<<B, TPB, 0, stream>>>(gx,
    m_ln_w, m_up_w, m_conv_w, m_conv_b, m_q_w, m_k_w, m_v_w,
    m_ig_w, m_ig_b, m_fg_w, m_fg_b, m_skip, m_on_w, m_down_w,
    s_ln_w, s_conv_w, s_conv_b, s_gate_w, s_rec_w, s_bias, s_gn_w,
    f_ln_w, f_up_w, f_down_w, post_ln_w, dense_w, dense_b,
    (float*)d_out);
}

// Round 5
// 1322.289 us; speedup vs baseline: 1.2967x; 1.2967x over previous
//
#include <hip/hip_runtime.h>
#include <math.h>

#define TPB 256

// per-wave LDS region (floats): KV[48][72] (k|v or wx) + IPT float2[48]
constexpr int WAVE_F = 3552;

// d_ws weight-table offsets (floats)
constexpr int OW_UP  = 0;       // [6][72][18]   up-proj transposed
constexpr int OW_AB  = 7776;    // [6][4][2][36] gate fold (A from xc, B from xm)
constexpr int OW_DWN = 9504;    // [6][18][36]   down-proj transposed
constexpr int OW_FUP = 13392;   // [128][18]     FFN up transposed
constexpr int OW_FDW = 15696;   // [18][64]      FFN down transposed

__device__ __forceinline__ float sigm(float v){ return 1.f/(1.f+__expf(-v)); }
__device__ __forceinline__ float siluf(float v){ return v/(1.f+__expf(-v)); }
__device__ __forceinline__ float logsig(float v){ return fminf(v,0.f) - log1pf(__expf(-fabsf(v))); }

extern "C" __global__ void prep_kernel(
    const float* __restrict__ up,  const float* __restrict__ qw, const float* __restrict__ kw,
    const float* __restrict__ vw,  const float* __restrict__ igw,const float* __restrict__ fgw,
    const float* __restrict__ dwn, const float* __restrict__ fup,const float* __restrict__ fdw,
    float* __restrict__ W)
{
  const int tid = threadIdx.x;
  for (int i=tid;i<7776;i+=TPB){ int mj=i/1296, r=i%1296, o=r/18, d=r%18; W[OW_UP+i]=up[mj*1296+d*72+o]; }
  for (int i=tid;i<1728;i+=TPB){
    int mj=i/288, r=i%288, gh=r/72, w2=(r%72)/36, c=r%36;
    int g=gh>>1,h=gh&1,n=c>>2,d=c&3;
    const float* gwp=(g? fgw:igw)+mj*216+h*108;
    float val=0.f;
    if(w2==0){ for(int o=0;o<4;++o) val += qw[mj*144+n*16+o*4+d]*gwp[n*4+o] + kw[mj*144+n*16+o*4+d]*gwp[36+n*4+o]; }
    else     { for(int o=0;o<4;++o) val += vw[mj*144+n*16+o*4+d]*gwp[72+n*4+o]; }
    W[OW_AB+i]=val;
  }
  for (int i=tid;i<3888;i+=TPB){ int mj=i/648, r=i%648, e=r/36, c=r%36; W[OW_DWN+i]=dwn[mj*648+c*18+e]; }
  for (int i=tid;i<2304;i+=TPB){ int f=i/18, d=i%18; W[OW_FUP+i]=fup[d*128+f]; }
  for (int i=tid;i<1152;i+=TPB){ int e=i/64, f=i%64; W[OW_FDW+i]=fdw[f*18+e]; }
}

__device__ __forceinline__ void mlstm(float (&x)[18], const int lane, float* KV, float* IPT,
    const float* __restrict__ lnw, const float* __restrict__ wup, const float* __restrict__ wab,
    const float* __restrict__ wdwn,const float* __restrict__ cw,  const float* __restrict__ cb,
    const float* __restrict__ qw,  const float* __restrict__ kw,  const float* __restrict__ vw,
    const float* __restrict__ igb, const float* __restrict__ fgb, const float* __restrict__ skp,
    const float* __restrict__ onw)
{
  // LN
  float mu=0.f;
  #pragma unroll
  for(int d=0;d<18;++d) mu+=x[d];
  mu*=(1.f/18.f);
  float var=0.f;
  #pragma unroll
  for(int d=0;d<18;++d){ float t=x[d]-mu; var+=t*t; }
  var*=(1.f/18.f);
  const float rr=rsqrtf(var+1e-5f);
  float h[18];
  #pragma unroll
  for(int d=0;d<18;++d) h[d]=(x[d]-mu)*rr*lnw[d];

  // up-proj -> xm, z (scalar weights, per-lane row)
  float xm[36], z[36];
  #pragma unroll
  for(int o=0;o<36;++o){
    const float* w=&wup[o*18]; float a=0.f;
    #pragma unroll
    for(int d=0;d<18;++d) a+=h[d]*w[d];
    xm[o]=a;
  }
  #pragma unroll
  for(int o=0;o<36;++o){
    const float* w=&wup[(36+o)*18]; float a=0.f;
    #pragma unroll
    for(int d=0;d<18;++d) a+=h[d]*w[d];
    z[o]=a;
  }
  if (lane>=48){
    #pragma unroll
    for(int c=0;c<36;++c) xm[c]=0.f;   // so conv wraparound shuffles read 0
  }

  // causal depthwise conv(k=4)+silu via shuffles
  float xc[36];
  #pragma unroll
  for(int c=0;c<36;++c){
    float x1=__shfl(xm[c], lane-1), x2=__shfl(xm[c], lane-2), x3=__shfl(xm[c], lane-3);
    float a = cb[c] + x3*cw[c*4] + x2*cw[c*4+1] + x1*cw[c*4+2] + xm[c]*cw[c*4+3];
    xc[c] = siluf(a);
  }

  // gates via folded weights
  float gi0=igb[0], gi1=igb[1], gf0=fgb[0], gf1=fgb[1];
  #pragma unroll
  for(int c=0;c<36;++c){
    gi0 += xc[c]*wab[  0+c] + xm[c]*wab[ 36+c];
    gi1 += xc[c]*wab[ 72+c] + xm[c]*wab[108+c];
    gf0 += xc[c]*wab[144+c] + xm[c]*wab[180+c];
    gf1 += xc[c]*wab[216+c] + xm[c]*wab[252+c];
  }

  // q in regs; k,v -> LDS (float4 chunks, n==c4, o==j)
  float q[36];
  #pragma unroll
  for(int c=0;c<36;++c){
    const int n=c>>2,o=c&3; const float* w=&qw[n*16+o*4]; const float* xb=&xc[n*4];
    q[c]=xb[0]*w[0]+xb[1]*w[1]+xb[2]*w[2]+xb[3]*w[3];
  }
  #pragma unroll
  for(int c4=0;c4<9;++c4){
    const float* xb=&xc[c4*4]; const float* mb=&xm[c4*4];
    float4 kt, vt;
    kt.x=xb[0]*kw[c4*16+ 0]+xb[1]*kw[c4*16+ 1]+xb[2]*kw[c4*16+ 2]+xb[3]*kw[c4*16+ 3];
    kt.y=xb[0]*kw[c4*16+ 4]+xb[1]*kw[c4*16+ 5]+xb[2]*kw[c4*16+ 6]+xb[3]*kw[c4*16+ 7];
    kt.z=xb[0]*kw[c4*16+ 8]+xb[1]*kw[c4*16+ 9]+xb[2]*kw[c4*16+10]+xb[3]*kw[c4*16+11];
    kt.w=xb[0]*kw[c4*16+12]+xb[1]*kw[c4*16+13]+xb[2]*kw[c4*16+14]+xb[3]*kw[c4*16+15];
    vt.x=mb[0]*vw[c4*16+ 0]+mb[1]*vw[c4*16+ 1]+mb[2]*vw[c4*16+ 2]+mb[3]*vw[c4*16+ 3];
    vt.y=mb[0]*vw[c4*16+ 4]+mb[1]*vw[c4*16+ 5]+mb[2]*vw[c4*16+ 6]+mb[3]*vw[c4*16+ 7];
    vt.z=mb[0]*vw[c4*16+ 8]+mb[1]*vw[c4*16+ 9]+mb[2]*vw[c4*16+10]+mb[3]*vw[c4*16+11];
    vt.w=mb[0]*vw[c4*16+12]+mb[1]*vw[c4*16+13]+mb[2]*vw[c4*16+14]+mb[3]*vw[c4*16+15];
    if (lane<48){
      *reinterpret_cast<float4*>(&KV[lane*72+4*c4])    = kt;
      *reinterpret_cast<float4*>(&KV[lane*72+36+4*c4]) = vt;
    }
  }

  // wave prefix scans: lfc (sum of logsig), cummax(ipre-lfc)
  float lf0=logsig(gf0), lf1=logsig(gf1);
  #pragma unroll
  for(int off=1; off<64; off<<=1){
    float t0=__shfl_up(lf0,off), t1=__shfl_up(lf1,off);
    if(lane>=off){ lf0+=t0; lf1+=t1; }
  }
  const float ipt0=gi0-lf0, ipt1=gi1-lf1;
  float u0=ipt0, u1=ipt1;
  #pragma unroll
  for(int off=1; off<64; off<<=1){
    float t0=__shfl_up(u0,off), t1=__shfl_up(u1,off);
    if(lane>=off){ u0=fmaxf(u0,t0); u1=fmaxf(u1,t1); }
  }
  if (lane<48){ float2 w2v{ipt0,ipt1}; *reinterpret_cast<float2*>(&IPT[2*lane])=w2v; }
  asm volatile("s_waitcnt lgkmcnt(0)" ::: "memory");

  // fused attention: both heads, t-loop over LDS broadcast rows
  float acc[36];
  #pragma unroll
  for(int d=0;d<36;++d) acc[d]=0.f;
  float rs0=0.f, rs1=0.f;
  const float rb0=-u0, rb1=-u1;
  for(int t=0;t<48;++t){
    const float2 ip = *reinterpret_cast<const float2*>(&IPT[2*t]);
    const float4* kr = reinterpret_cast<const float4*>(&KV[t*72]);
    const float4* vr = reinterpret_cast<const float4*>(&KV[t*72+36]);
    const float e0=__expf(fminf(rb0+ip.x,0.f)), e1=__expf(fminf(rb1+ip.y,0.f));
    float qk0=0.f, qk1=0.f;
    #pragma unroll
    for(int j=0;j<9;++j){
      const float4 kk = kr[j];
      if (j<4)      { qk0 += kk.x*q[4*j]+kk.y*q[4*j+1]+kk.z*q[4*j+2]+kk.w*q[4*j+3]; }
      else if (j==4){ qk0 += kk.x*q[16]+kk.y*q[17]; qk1 += kk.z*q[18]+kk.w*q[19]; }
      else          { qk1 += kk.x*q[4*j]+kk.y*q[4*j+1]+kk.z*q[4*j+2]+kk.w*q[4*j+3]; }
    }
    const bool on = (t<=lane);
    const float c0 = on ? qk0*0.23570226039551584f*e0 : 0.f;
    const float c1 = on ? qk1*0.23570226039551584f*e1 : 0.f;
    rs0+=c0; rs1+=c1;
    #pragma unroll
    for(int j=0;j<9;++j){
      const float4 vv = vr[j];
      if (j<4)      { acc[4*j]+=c0*vv.x; acc[4*j+1]+=c0*vv.y; acc[4*j+2]+=c0*vv.z; acc[4*j+3]+=c0*vv.w; }
      else if (j==4){ acc[16]+=c0*vv.x; acc[17]+=c0*vv.y; acc[18]+=c1*vv.z; acc[19]+=c1*vv.w; }
      else          { acc[4*j]+=c1*vv.x; acc[4*j+1]+=c1*vv.y; acc[4*j+2]+=c1*vv.z; acc[4*j+3]+=c1*vv.w; }
    }
  }

  // normalize, per-head LN * onw, hst, down-proj
  const float mr0=lf0+u0, mr1=lf1+u1;
  const float ninv0 = 1.f/(fmaxf(fabsf(rs0), __expf(-mr0))+1e-6f);
  const float ninv1 = 1.f/(fmaxf(fabsf(rs1), __expf(-mr1))+1e-6f);
  #pragma unroll
  for(int d=0;d<18;++d){ acc[d]*=ninv0; acc[18+d]*=ninv1; }
  float mu0=0.f, mu1=0.f;
  #pragma unroll
  for(int d=0;d<18;++d){ mu0+=acc[d]; mu1+=acc[18+d]; }
  mu0*=(1.f/18.f); mu1*=(1.f/18.f);
  float v0=0.f, v1=0.f;
  #pragma unroll
  for(int d=0;d<18;++d){ float a=acc[d]-mu0, b=acc[18+d]-mu1; v0+=a*a; v1+=b*b; }
  const float r0=rsqrtf(v0*(1.f/18.f)+1e-5f), r1=rsqrtf(v1*(1.f/18.f)+1e-5f);
  #pragma unroll
  for(int c=0;c<36;++c){
    const float hn = (c<18) ? (acc[c]-mu0)*r0*onw[c] : (acc[c]-mu1)*r1*onw[c];
    acc[c] = (hn + skp[c]*xc[c]) * siluf(z[c]);
  }
  #pragma unroll
  for(int e=0;e<18;++e){
    const float* w=&wdwn[e*36]; float a=0.f;
    #pragma unroll
    for(int c=0;c<36;++c) a+=acc[c]*w[c];
    x[e]+=a;
  }
}

__device__ __forceinline__ void slstm(float (&x)[18], const int lane, float* KV,
    const float* __restrict__ lnw, const float* __restrict__ cw, const float* __restrict__ cb,
    const float* __restrict__ gw,  const float* __restrict__ rw, const float* __restrict__ gb,
    const float* __restrict__ gnw, const float* __restrict__ flnw,
    const float* __restrict__ wfup,const float* __restrict__ wfdw)
{
  // LN
  float mu=0.f;
  #pragma unroll
  for(int d=0;d<18;++d) mu+=x[d];
  mu*=(1.f/18.f);
  float var=0.f;
  #pragma unroll
  for(int d=0;d<18;++d){ float t=x[d]-mu; var+=t*t; }
  var*=(1.f/18.f);
  const float rr=rsqrtf(var+1e-5f);
  float h[18];
  #pragma unroll
  for(int d=0;d<18;++d) h[d]=(lane<48)?(x[d]-mu)*rr*lnw[d]:0.f;

  // conv + silu
  float hc[18];
  #pragma unroll
  for(int c=0;c<18;++c){
    float x1=__shfl(h[c], lane-1), x2=__shfl(h[c], lane-2), x3=__shfl(h[c], lane-3);
    float a=cb[c]+x3*cw[c*4]+x2*cw[c*4+1]+x1*cw[c*4+2]+h[c]*cw[c*4+3];
    hc[c]=siluf(a);
  }

  // wx -> KV rows: slot (g*2+hh)*9+e
  #pragma unroll
  for(int q4=0;q4<18;++q4){
    float4 t;
    #pragma unroll
    for(int j=0;j<4;++j){
      const int idx=4*q4+j, g=idx/18, hh=(idx%18)/9, e=idx%9;
      const float* inp = (g<2 ? hc : h) + hh*9;
      const float* w=&gw[idx*9];
      float a=gb[idx];
      #pragma unroll
      for(int d=0;d<9;++d) a+=inp[d]*w[d];
      (&t.x)[j]=a;
    }
    if (lane<48) *reinterpret_cast<float4*>(&KV[lane*72+4*q4])=t;
  }
  asm volatile("s_waitcnt lgkmcnt(0)" ::: "memory");

  // scan, one head at a time, wave-synchronous; y written back into consumed slots
  for(int hh=0;hh<2;++hh){
    const int li = (lane<36)? lane : 0;
    const int g=li/9, e=li%9;
    float rwreg[9];
    #pragma unroll
    for(int d=0;d<9;++d) rwreg[d]=rw[((hh*9+d)*4+g)*9+e];
    float yv=0.f,cv=0.f,nv=0.f,mv=0.f;
    for(int st=0;st<48;++st){
      float raw = KV[st*72 + (g*2+hh)*9 + e];
      #pragma unroll
      for(int d=0;d<9;++d) raw += __shfl(yv,d)*rwreg[d];
      const float i_=__shfl(raw,e), f_=__shfl(raw,9+e), z_=__shfl(raw,18+e), o_=__shfl(raw,27+e);
      const float lfm=mv+logsig(f_);
      const float mn=fmaxf(i_,lfm);
      const float ig=__expf(i_-mn), fg=__expf(lfm-mn);
      cv=fg*cv+ig*tanhf(z_);
      nv=fg*nv+ig; mv=mn;
      yv=sigm(o_)*cv/nv;
      if(lane<9) KV[st*72+hh*9+lane]=yv;
    }
  }
  asm volatile("s_waitcnt lgkmcnt(0)" ::: "memory");

  // group norm (per head over 9) + residual
  if (lane<48){
    #pragma unroll
    for(int hh=0;hh<2;++hh){
      float yv_[9]; float m2=0.f;
      #pragma unroll
      for(int e=0;e<9;++e){ yv_[e]=KV[lane*72+hh*9+e]; m2+=yv_[e]; }
      m2*=(1.f/9.f);
      float vv=0.f;
      #pragma unroll
      for(int e=0;e<9;++e){ float t=yv_[e]-m2; vv+=t*t; }
      const float r2=rsqrtf(vv*(1.f/9.f)+1e-5f);
      #pragma unroll
      for(int e=0;e<9;++e) x[hh*9+e]+=(yv_[e]-m2)*r2*gnw[hh*9+e];
    }
  }

  // FFN: LN -> h2; act[64] in regs; down + residual
  float mu2=0.f;
  #pragma unroll
  for(int d=0;d<18;++d) mu2+=x[d];
  mu2*=(1.f/18.f);
  float var2=0.f;
  #pragma unroll
  for(int d=0;d<18;++d){ float t=x[d]-mu2; var2+=t*t; }
  var2*=(1.f/18.f);
  const float rr2=rsqrtf(var2+1e-5f);
  float h2[18];
  #pragma unroll
  for(int d=0;d<18;++d) h2[d]=(x[d]-mu2)*rr2*flnw[d];

  float act[64];
  #pragma unroll
  for(int f=0;f<64;++f){
    const float* wg=&wfup[f*18]; const float* wu=&wfup[(64+f)*18];
    float ug=0.f, uu=0.f;
    #pragma unroll
    for(int d=0;d<18;++d){ ug+=h2[d]*wg[d]; uu+=h2[d]*wu[d]; }
    const float ge=0.5f*ug*(1.f+erff(ug*0.70710678118654752f));
    act[f]=ge*uu;
  }
  #pragma unroll
  for(int e=0;e<18;++e){
    const float* w=&wfdw[e*64]; float a=0.f;
    #pragma unroll
    for(int f=0;f<64;++f) a+=act[f]*w[f];
    x[e]+=a;
  }
}

extern "C" __global__ void __launch_bounds__(TPB, 2)
xlstm_kernel(const float* __restrict__ gx,
             const float* __restrict__ m_ln_w,  const float* __restrict__ m_conv_w,
             const float* __restrict__ m_conv_b,const float* __restrict__ m_q_w,
             const float* __restrict__ m_k_w,   const float* __restrict__ m_v_w,
             const float* __restrict__ m_ig_b,  const float* __restrict__ m_fg_b,
             const float* __restrict__ m_skip,  const float* __restrict__ m_on_w,
             const float* __restrict__ s_ln_w,  const float* __restrict__ s_conv_w,
             const float* __restrict__ s_conv_b,const float* __restrict__ s_gate_w,
             const float* __restrict__ s_rec_w, const float* __restrict__ s_bias,
             const float* __restrict__ s_gn_w,  const float* __restrict__ f_ln_w,
             const float* __restrict__ post_ln_w, const float* __restrict__ dense_w,
             const float* __restrict__ dense_b, const float* __restrict__ W,
             float* __restrict__ gout, const int Btot)
{
  __shared__ float L[4*WAVE_F];
  const int lane = threadIdx.x & 63;
  const int wv   = threadIdx.x >> 6;
  const int b    = blockIdx.x*4 + wv;
  if (b >= Btot) return;
  float* KV  = &L[wv*WAVE_F];
  float* IPT = KV + 3456;

  float x[18];
  #pragma unroll
  for(int d=0;d<18;++d) x[d] = (lane<48) ? gx[b*864 + lane*18 + d] : 0.f;

  int mj=0;
  #pragma unroll 1
  for(int blk=0; blk<7; ++blk){
    if (blk==1){
      slstm(x, lane, KV, s_ln_w, s_conv_w, s_conv_b, s_gate_w, s_rec_w, s_bias,
            s_gn_w, f_ln_w, W+OW_FUP, W+OW_FDW);
    } else {
      mlstm(x, lane, KV, IPT,
            m_ln_w+mj*18, W+OW_UP+mj*1296, W+OW_AB+mj*288, W+OW_DWN+mj*648,
            m_conv_w+mj*144, m_conv_b+mj*36,
            m_q_w+mj*144, m_k_w+mj*144, m_v_w+mj*144,
            m_ig_b+mj*2, m_fg_b+mj*2, m_skip+mj*36, m_on_w+mj*36);
      ++mj;
    }
  }

  // post-LN + dense(18->1), zero s<24
  if (lane<48){
    float mu=0.f;
    #pragma unroll
    for(int d=0;d<18;++d) mu+=x[d];
    mu*=(1.f/18.f);
    float var=0.f;
    #pragma unroll
    for(int d=0;d<18;++d){ float t=x[d]-mu; var+=t*t; }
    var*=(1.f/18.f);
    const float rr=rsqrtf(var+1e-5f);
    float acc=dense_b[0];
    #pragma unroll
    for(int d=0;d<18;++d) acc += (x[d]-mu)*rr*post_ln_w[d]*dense_w[d];
    gout[b*48+lane] = (lane<24) ? 0.f : acc;
  }
}

extern "C" void kernel_launch(void* const* d_in, const int* in_sizes, int n_in,
                              void* d_out, int out_size, void* d_ws, size_t ws_size,
                              hipStream_t stream)
{
  const float* gx        = (const float*)d_in[0];
  const float* m_ln_w    = (const float*)d_in[1];
  const float* m_up_w    = (const float*)d_in[2];
  const float* m_conv_w  = (const float*)d_in[3];
  const float* m_conv_b  = (const float*)d_in[4];
  const float* m_q_w     = (const float*)d_in[5];
  const float* m_k_w     = (const float*)d_in[6];
  const float* m_v_w     = (const float*)d_in[7];
  const float* m_ig_w    = (const float*)d_in[8];
  const float* m_ig_b    = (const float*)d_in[9];
  const float* m_fg_w    = (const float*)d_in[10];
  const float* m_fg_b    = (const float*)d_in[11];
  const float* m_skip    = (const float*)d_in[12];
  const float* m_on_w    = (const float*)d_in[13];
  const float* m_down_w  = (const float*)d_in[14];
  const float* s_ln_w    = (const float*)d_in[15];
  const float* s_conv_w  = (const float*)d_in[16];
  const float* s_conv_b  = (const float*)d_in[17];
  const float* s_gate_w  = (const float*)d_in[18];
  const float* s_rec_w   = (const float*)d_in[19];
  const float* s_bias    = (const float*)d_in[20];
  const float* s_gn_w    = (const float*)d_in[21];
  const float* f_ln_w    = (const float*)d_in[22];
  const float* f_up_w    = (const float*)d_in[23];
  const float* f_down_w  = (const float*)d_in[24];
  const float* post_ln_w = (const float*)d_in[25];
  const float* dense_w   = (const float*)d_in[26];
  const float* dense_b   = (const float*)d_in[27];

  float* W = (float*)d_ws;
  const int B = in_sizes[0] / (48*18);

  prep_kernel<<<1, TPB, 0, stream>>>(m_up_w, m_q_w, m_k_w, m_v_w, m_ig_w, m_fg_w,
                                     m_down_w, f_up_w, f_down_w, W);
  xlstm_kernel<<<(B+3)/4, TPB, 0, stream>>>(gx,
    m_ln_w, m_conv_w, m_conv_b, m_q_w, m_k_w, m_v_w,
    m_ig_b, m_fg_b, m_skip, m_on_w,
    s_ln_w, s_conv_w, s_conv_b, s_gate_w, s_rec_w, s_bias, s_gn_w,
    f_ln_w, post_ln_w, dense_w, dense_b, W, (float*)d_out, B);
}